// Round 1
// baseline (693.595 us; speedup 1.0000x reference)
//
#include <hip/hip_runtime.h>

#define N_NODES 100000
#define N_EDGES 1600000
#define HID 128

// ---------------- CSR build ----------------

__global__ void k_hist(const int* __restrict__ row, int* __restrict__ deg) {
    int e = blockIdx.x * blockDim.x + threadIdx.x;
    if (e < N_EDGES) atomicAdd(&deg[row[e]], 1);
}

// Per-block exclusive scan (Hillis-Steele in LDS), block sums out.
__global__ void k_scan1(const int* __restrict__ deg, int* __restrict__ excl,
                        int* __restrict__ bsum) {
    __shared__ int s[256];
    int t = threadIdx.x;
    int i = blockIdx.x * 256 + t;
    int v = (i < N_NODES) ? deg[i] : 0;
    s[t] = v;
    __syncthreads();
    for (int off = 1; off < 256; off <<= 1) {
        int x = (t >= off) ? s[t - off] : 0;
        __syncthreads();
        s[t] += x;
        __syncthreads();
    }
    if (i < N_NODES) excl[i] = s[t] - v;
    if (t == 255) bsum[blockIdx.x] = s[255];
}

// Single-block exclusive scan of block sums (nb <= 512).
__global__ void k_scan2(int* __restrict__ bsum, int nb) {
    __shared__ int s[512];
    int t = threadIdx.x;
    int v = (t < nb) ? bsum[t] : 0;
    s[t] = v;
    __syncthreads();
    for (int off = 1; off < 512; off <<= 1) {
        int x = (t >= off) ? s[t - off] : 0;
        __syncthreads();
        s[t] += x;
        __syncthreads();
    }
    if (t < nb) bsum[t] = s[t] - v;
}

// Add block offsets in place; init next[] cursors; finalize row_ptr[N].
__global__ void k_scan3(int* __restrict__ row_ptr, const int* __restrict__ bsum,
                        int* __restrict__ nxt) {
    int i = blockIdx.x * 256 + threadIdx.x;
    if (i < N_NODES) {
        int v = row_ptr[i] + bsum[blockIdx.x];
        row_ptr[i] = v;
        nxt[i] = v;
    }
    if (i == 0) row_ptr[N_NODES] = N_EDGES;
}

__global__ void k_scatter(const int* __restrict__ row, const int* __restrict__ col,
                          const float* __restrict__ vals, int* __restrict__ nxt,
                          int* __restrict__ cs, float* __restrict__ vs) {
    int e = blockIdx.x * blockDim.x + threadIdx.x;
    if (e < N_EDGES) {
        int p = atomicAdd(&nxt[row[e]], 1);
        cs[p] = col[e];
        vs[p] = vals[e];
    }
}

// ---------------- GEMM1: H = relu(X @ W_in + b_in) ----------------
// Block: 256 threads, 64-row x 128-col tile. X tile staged in LDS (contiguous
// 32KB), W read through L1/L2 (64KB, coalesced float4). Thread = 8 rows x 4 cols.
__global__ __launch_bounds__(256) void k_gemm_in(const float* __restrict__ X,
                                                 const float* __restrict__ W,
                                                 const float* __restrict__ b,
                                                 float* __restrict__ H) {
    __shared__ float Xs[64 * HID];
    int r0 = blockIdx.x * 64;
    int tid = threadIdx.x;
    int rows = N_NODES - r0;
    if (rows > 64) rows = 64;
    int nf4 = rows * 32;

    const float4* Xg = (const float4*)(X + (size_t)r0 * HID);
    float4* Xs4 = (float4*)Xs;
#pragma unroll
    for (int i = 0; i < 8; i++) {
        int idx = tid + i * 256;
        float4 v = (idx < nf4) ? Xg[idx] : make_float4(0.f, 0.f, 0.f, 0.f);
        Xs4[idx] = v;
    }
    __syncthreads();

    int tx = tid & 31, ty = tid >> 5;
    const float4* W4 = (const float4*)W;
    float4 acc[8];
#pragma unroll
    for (int i = 0; i < 8; i++) acc[i] = make_float4(0.f, 0.f, 0.f, 0.f);

    for (int k = 0; k < HID; k += 4) {
        float4 x[8];
#pragma unroll
        for (int i = 0; i < 8; i++) x[i] = Xs4[(ty * 8 + i) * 32 + (k >> 2)];
#pragma unroll
        for (int kk = 0; kk < 4; kk++) {
            float4 w = W4[(k + kk) * 32 + tx];
#pragma unroll
            for (int i = 0; i < 8; i++) {
                float xs = (kk == 0) ? x[i].x : (kk == 1) ? x[i].y : (kk == 2) ? x[i].z : x[i].w;
                acc[i].x += xs * w.x;
                acc[i].y += xs * w.y;
                acc[i].z += xs * w.z;
                acc[i].w += xs * w.w;
            }
        }
    }

    float4 bb = ((const float4*)b)[tx];
#pragma unroll
    for (int i = 0; i < 8; i++) {
        int r = r0 + ty * 8 + i;
        if (r < N_NODES) {
            float4 h;
            h.x = fmaxf(acc[i].x + bb.x, 0.f);
            h.y = fmaxf(acc[i].y + bb.y, 0.f);
            h.z = fmaxf(acc[i].z + bb.z, 0.f);
            h.w = fmaxf(acc[i].w + bb.w, 0.f);
            ((float4*)H)[(size_t)r * 32 + tx] = h;
        }
    }
}

// ---------------- SpMM: one wave per row, register accumulate ----------------
__global__ __launch_bounds__(256) void k_spmm(const int* __restrict__ row_ptr,
                                              const int* __restrict__ cs,
                                              const float* __restrict__ vs,
                                              const float* __restrict__ Hin,
                                              float* __restrict__ Hout) {
    int wid = (blockIdx.x * blockDim.x + threadIdx.x) >> 6;
    int lane = threadIdx.x & 63;
    if (wid >= N_NODES) return;
    int s = __builtin_amdgcn_readfirstlane(row_ptr[wid]);
    int e = __builtin_amdgcn_readfirstlane(row_ptr[wid + 1]);
    const float2* H2 = (const float2*)Hin;
    float2 acc = make_float2(0.f, 0.f);
    for (int j = s; j < e; ++j) {
        int c = cs[j];
        float v = vs[j];
        float2 h = H2[c * 64 + lane];
        acc.x += v * h.x;
        acc.y += v * h.y;
    }
    ((float2*)Hout)[wid * 64 + lane] = acc;
}

// ------- Final: out = relu(AH@W1 + A2H@W2) @ W_out + b_out (fused) -------
__global__ __launch_bounds__(256) void k_gemm_out(const float* __restrict__ AH,
                                                  const float* __restrict__ A2H,
                                                  const float* __restrict__ W1,
                                                  const float* __restrict__ W2,
                                                  const float* __restrict__ Wout,
                                                  const float* __restrict__ bout,
                                                  float* __restrict__ out) {
    __shared__ float As[64 * HID];
    __shared__ float Bs[64 * HID];
    int r0 = blockIdx.x * 64;
    int tid = threadIdx.x;
    int rows = N_NODES - r0;
    if (rows > 64) rows = 64;
    int nf4 = rows * 32;

    const float4* Ag = (const float4*)(AH + (size_t)r0 * HID);
    const float4* Bg = (const float4*)(A2H + (size_t)r0 * HID);
#pragma unroll
    for (int i = 0; i < 8; i++) {
        int idx = tid + i * 256;
        float4 a = (idx < nf4) ? Ag[idx] : make_float4(0.f, 0.f, 0.f, 0.f);
        float4 b = (idx < nf4) ? Bg[idx] : make_float4(0.f, 0.f, 0.f, 0.f);
        ((float4*)As)[idx] = a;
        ((float4*)Bs)[idx] = b;
    }
    __syncthreads();

    int tx = tid & 31, ty = tid >> 5;
    const float4* W14 = (const float4*)W1;
    const float4* W24 = (const float4*)W2;
    const float4* As4 = (const float4*)As;
    const float4* Bs4 = (const float4*)Bs;
    float4 acc[8];
#pragma unroll
    for (int i = 0; i < 8; i++) acc[i] = make_float4(0.f, 0.f, 0.f, 0.f);

    for (int k = 0; k < HID; k += 4) {
        float4 a[8], b[8];
#pragma unroll
        for (int i = 0; i < 8; i++) {
            a[i] = As4[(ty * 8 + i) * 32 + (k >> 2)];
            b[i] = Bs4[(ty * 8 + i) * 32 + (k >> 2)];
        }
#pragma unroll
        for (int kk = 0; kk < 4; kk++) {
            float4 w1 = W14[(k + kk) * 32 + tx];
            float4 w2 = W24[(k + kk) * 32 + tx];
#pragma unroll
            for (int i = 0; i < 8; i++) {
                float as = (kk == 0) ? a[i].x : (kk == 1) ? a[i].y : (kk == 2) ? a[i].z : a[i].w;
                float bs = (kk == 0) ? b[i].x : (kk == 1) ? b[i].y : (kk == 2) ? b[i].z : b[i].w;
                acc[i].x += as * w1.x + bs * w2.x;
                acc[i].y += as * w1.y + bs * w2.y;
                acc[i].z += as * w1.z + bs * w2.z;
                acc[i].w += as * w1.w + bs * w2.w;
            }
        }
    }

    float4 wo = ((const float4*)Wout)[tx];
    float bo = bout[0];
    float partial[8];
#pragma unroll
    for (int i = 0; i < 8; i++) {
        float hx = fmaxf(acc[i].x, 0.f);
        float hy = fmaxf(acc[i].y, 0.f);
        float hz = fmaxf(acc[i].z, 0.f);
        float hw = fmaxf(acc[i].w, 0.f);
        partial[i] = hx * wo.x + hy * wo.y + hz * wo.z + hw * wo.w;
    }
    // reduce across the 32 col-groups (xor masks 1..16 stay within each half-wave)
#pragma unroll
    for (int off = 1; off < 32; off <<= 1) {
#pragma unroll
        for (int i = 0; i < 8; i++) partial[i] += __shfl_xor(partial[i], off, 64);
    }
    if (tx == 0) {
#pragma unroll
        for (int i = 0; i < 8; i++) {
            int r = r0 + ty * 8 + i;
            if (r < N_NODES) out[r] = partial[i] + bo;
        }
    }
}

// ---------------- launch ----------------

extern "C" void kernel_launch(void* const* d_in, const int* in_sizes, int n_in,
                              void* d_out, int out_size, void* d_ws, size_t ws_size,
                              hipStream_t stream) {
    const float* X    = (const float*)d_in[0];
    const int*   row  = (const int*)d_in[1];
    const int*   col  = (const int*)d_in[2];
    const float* vals = (const float*)d_in[3];
    const float* W_in = (const float*)d_in[4];
    const float* b_in = (const float*)d_in[5];
    const float* W1   = (const float*)d_in[6];
    const float* W2   = (const float*)d_in[7];
    const float* Wout = (const float*)d_in[8];
    const float* bout = (const float*)d_in[9];
    float* out = (float*)d_out;

    char* ws = (char*)d_ws;
    size_t off = 0;
    auto alloc = [&](size_t bytes) -> void* {
        void* p = ws + off;
        off += (bytes + 511) & ~(size_t)511;
        return p;
    };
    float* B0      = (float*)alloc((size_t)N_NODES * HID * 4);  // H, then A2H
    float* B1      = (float*)alloc((size_t)N_NODES * HID * 4);  // AH
    int*   deg     = (int*)alloc((size_t)N_NODES * 4);
    int*   row_ptr = (int*)alloc((size_t)(N_NODES + 1) * 4);
    int*   nxt     = (int*)alloc((size_t)N_NODES * 4);
    int*   bsum    = (int*)alloc(512 * 4);
    int*   cs      = (int*)alloc((size_t)N_EDGES * 4);
    float* vs      = (float*)alloc((size_t)N_EDGES * 4);

    hipMemsetAsync(deg, 0, (size_t)N_NODES * 4, stream);

    int eblk = (N_EDGES + 255) / 256;
    int nb = (N_NODES + 255) / 256;  // 391
    k_hist<<<eblk, 256, 0, stream>>>(row, deg);
    k_scan1<<<nb, 256, 0, stream>>>(deg, row_ptr, bsum);
    k_scan2<<<1, 512, 0, stream>>>(bsum, nb);
    k_scan3<<<nb, 256, 0, stream>>>(row_ptr, bsum, nxt);
    k_scatter<<<eblk, 256, 0, stream>>>(row, col, vals, nxt, cs, vs);

    int gblk = (N_NODES + 63) / 64;  // 1563
    k_gemm_in<<<gblk, 256, 0, stream>>>(X, W_in, b_in, B0);

    int sblk = (N_NODES + 3) / 4;  // 4 rows (waves) per block
    k_spmm<<<sblk, 256, 0, stream>>>(row_ptr, cs, vs, B0, B1);  // AH = A*H
    k_spmm<<<sblk, 256, 0, stream>>>(row_ptr, cs, vs, B1, B0);  // A2H = A*AH

    k_gemm_out<<<gblk, 256, 0, stream>>>(B1, B0, W1, W2, Wout, bout, out);
}